// Round 2
// baseline (107.558 us; speedup 1.0000x reference)
//
#include <hip/hip_runtime.h>
#include <hip/hip_bf16.h>

typedef __attribute__((ext_vector_type(8))) short short8;
typedef __attribute__((ext_vector_type(4))) float floatx4;

#define NB 4096
#define NF 1024
#define NR 64
#define NK 32
#define ND 16
#define HALF_D_LOG2PI 14.702988531274762f

// bf16 helpers (finite values only; round-to-nearest-even)
__device__ __forceinline__ unsigned f2bf_bits(float f) {
    unsigned u = __float_as_uint(f);
    return (u + 0x7fffu + ((u >> 16) & 1u)) >> 16;
}
__device__ __forceinline__ float bf_bits2f(unsigned b) {
    return __uint_as_float(b << 16);
}

// ---------------- K1: prep --------------------------------------------------
// W[r][K=64][kk=32] with K slots [A(x2h) A(x2l) B(xh) B(xl)], written directly
// in MFMA B-fragment order: wfrag[((r*2+ks)*2+nt)*64 + lane]*8 + j
__global__ __launch_bounds__(256) void prep_kernel(
    const float* __restrict__ means, const float* __restrict__ scales,
    unsigned short* __restrict__ wfrag, float* __restrict__ cv)
{
    int p = blockIdx.x * 256 + threadIdx.x;   // p = r*32 + kk
    if (p >= NR * NK) return;
    int n  = p & 15;          // kk & 15
    int nt = (p >> 4) & 1;    // kk >> 4
    int r  = p >> 5;

    const float* m = means  + (size_t)p * ND;
    const float* s = scales + (size_t)p * ND;
    float Av[ND], Bv[ND];
    float csum = 0.f;
#pragma unroll
    for (int d = 0; d < ND; ++d) {
        float sd = s[d], md = m[d];
        float a  = 1.0f / sd;
        float a2 = a * a;
        Av[d] = -0.5f * a2;
        Bv[d] = md * a2;
        float c = md * a;
        csum += -0.5f * c * c - logf(sd);
    }
    cv[p] = csum - HALF_D_LOG2PI;

#pragma unroll
    for (int slot = 0; slot < 4; ++slot) {
        int ks = slot >> 1;
#pragma unroll
        for (int d = 0; d < ND; ++d) {
            int Kin  = (slot & 1) * 16 + d;   // K index within this ks half (0..31)
            int quad = Kin >> 3;
            int j    = Kin & 7;
            int lane = quad * 16 + n;
            size_t idx = ((((size_t)r * 2 + ks) * 2 + nt) * 64 + lane) * 8 + j;
            float v = (slot < 2) ? Av[d] : Bv[d];
            wfrag[idx] = (unsigned short)f2bf_bits(v);
        }
    }
}

// ---------------- K2: gather + transform ------------------------------------
// Xg[b][r] = 64 bf16 = [x2h d0..15 | x2l | xh | xl], row addr:
//   ((b>>4)*NR + r)*16 + (b&15), 128 B per row (A-fragment friendly)
__global__ __launch_bounds__(256) void gather_kernel(
    const float* __restrict__ x, const int* __restrict__ regions,
    unsigned short* __restrict__ xg)
{
    __shared__ float xs[8][NF];       // 32 KB
    __shared__ int   ridx[NR * ND];   // 4 KB

    const int t  = threadIdx.x;
    const int b0 = blockIdx.x * 8;

    for (int j = t; j < NR * ND; j += 256) ridx[j] = regions[j];
    {
        const float4* src = (const float4*)(x + (size_t)b0 * NF);
        float4* dst = (float4*)(&xs[0][0]);
#pragma unroll
        for (int j = t; j < 8 * NF / 4; j += 256) dst[j] = src[j];
    }
    __syncthreads();

#pragma unroll
    for (int pi = 0; pi < 2; ++pi) {
        int p  = t + pi * 256;        // 512 pairs: (b_local, r)
        int r  = p & 63;
        int bl = p >> 6;
        int b  = b0 + bl;
        size_t row = ((size_t)(b >> 4) * NR + r) * 16 + (b & 15);

        unsigned pk[32];              // 64 bf16 packed as 32 dwords
#pragma unroll
        for (int d = 0; d < ND; d += 2) {
            float xv0 = xs[bl][ridx[r * ND + d]];
            float xv1 = xs[bl][ridx[r * ND + d + 1]];
            float q0 = xv0 * xv0, q1 = xv1 * xv1;
            unsigned x2h0 = f2bf_bits(q0), x2h1 = f2bf_bits(q1);
            unsigned x2l0 = f2bf_bits(q0 - bf_bits2f(x2h0));
            unsigned x2l1 = f2bf_bits(q1 - bf_bits2f(x2h1));
            unsigned xh0  = f2bf_bits(xv0), xh1 = f2bf_bits(xv1);
            unsigned xl0  = f2bf_bits(xv0 - bf_bits2f(xh0));
            unsigned xl1  = f2bf_bits(xv1 - bf_bits2f(xh1));
            int di = d >> 1;
            pk[0 * 8 + di] = x2h0 | (x2h1 << 16);
            pk[1 * 8 + di] = x2l0 | (x2l1 << 16);
            pk[2 * 8 + di] = xh0  | (xh1  << 16);
            pk[3 * 8 + di] = xl0  | (xl1  << 16);
        }
        uint4* gdst = (uint4*)(xg + row * 64);
#pragma unroll
        for (int q = 0; q < 8; ++q) gdst[q] = ((uint4*)pk)[q];
    }
}

// ---------------- K3: MFMA GEMM ---------------------------------------------
// out[b][r][kk] = MFMA(Xg, W) + C.  Block: 64 b (4 waves x 16), 8 r's, 32 k.
__global__ __launch_bounds__(256) void gemm_kernel(
    const unsigned short* __restrict__ xg,
    const unsigned short* __restrict__ wfrag,
    const float* __restrict__ cv,
    float* __restrict__ out)
{
    const int t    = threadIdx.x;
    const int w    = t >> 6;
    const int L    = t & 63;
    const int m    = L & 15;
    const int quad = L >> 4;
    const int bt16 = blockIdx.x * 4 + w;
    const int r0   = blockIdx.y * 8;

    const short* xgs = (const short*)xg;
    const short* wfs = (const short*)wfrag;

#pragma unroll 2
    for (int i = 0; i < 8; ++i) {
        int r = r0 + i;
        size_t arow = (((size_t)bt16 * NR + r) * 16 + m) * 64 + quad * 8;
        short8 a0 = *(const short8*)(xgs + arow);        // K-step 0
        short8 a1 = *(const short8*)(xgs + arow + 32);   // K-step 1
        size_t wb = ((size_t)r * 4) * 512 + L * 8;
        short8 w00 = *(const short8*)(wfs + wb);          // ks0 nt0
        short8 w01 = *(const short8*)(wfs + wb + 512);    // ks0 nt1
        short8 w10 = *(const short8*)(wfs + wb + 1024);   // ks1 nt0
        short8 w11 = *(const short8*)(wfs + wb + 1536);   // ks1 nt1

        floatx4 acc0 = {0.f, 0.f, 0.f, 0.f};
        floatx4 acc1 = {0.f, 0.f, 0.f, 0.f};
        acc0 = __builtin_amdgcn_mfma_f32_16x16x32_bf16(a0, w00, acc0, 0, 0, 0);
        acc0 = __builtin_amdgcn_mfma_f32_16x16x32_bf16(a1, w10, acc0, 0, 0, 0);
        acc1 = __builtin_amdgcn_mfma_f32_16x16x32_bf16(a0, w01, acc1, 0, 0, 0);
        acc1 = __builtin_amdgcn_mfma_f32_16x16x32_bf16(a1, w11, acc1, 0, 0, 0);

        float c0 = cv[r * NK + m];
        float c1 = cv[r * NK + 16 + m];
        int brow = bt16 * 16 + quad * 4;
#pragma unroll
        for (int g = 0; g < 4; ++g) {
            size_t ob = (size_t)(brow + g) * (NR * NK) + (size_t)r * NK;
            out[ob + m]      = acc0[g] + c0;
            out[ob + 16 + m] = acc1[g] + c1;
        }
    }
}

extern "C" void kernel_launch(void* const* d_in, const int* in_sizes, int n_in,
                              void* d_out, int out_size, void* d_ws, size_t ws_size,
                              hipStream_t stream) {
    const float* x       = (const float*)d_in[0];
    const int*   regions = (const int*)d_in[1];
    const float* means   = (const float*)d_in[2];
    const float* scales  = (const float*)d_in[3];
    float* out = (float*)d_out;

    char* ws = (char*)d_ws;
    unsigned short* wfrag = (unsigned short*)ws;                  // 256 KB
    float*          cvp   = (float*)(ws + 262144);                // 8 KB
    unsigned short* xgp   = (unsigned short*)(ws + 262144 + 8192);// 33.6 MB

    prep_kernel<<<dim3((NR * NK + 255) / 256), 256, 0, stream>>>(means, scales, wfrag, cvp);
    gather_kernel<<<dim3(NB / 8), 256, 0, stream>>>(x, regions, xgp);
    gemm_kernel<<<dim3(NB / 64, 8), 256, 0, stream>>>(xgp, wfrag, cvp, out);
}

// Round 3
// 89.998 us; speedup vs baseline: 1.1951x; 1.1951x over previous
//
#include <hip/hip_runtime.h>

typedef __attribute__((ext_vector_type(8))) short short8;
typedef __attribute__((ext_vector_type(4))) float floatx4;

#define NB 4096
#define NF 1024
#define NR 64
#define NK 32
#define ND 16
#define HALF_D_LOG2PI 14.702988531274762f

// bf16 helpers (finite values only; round-to-nearest-even)
__device__ __forceinline__ unsigned f2bf_bits(float f) {
    unsigned u = __float_as_uint(f);
    return (u + 0x7fffu + ((u >> 16) & 1u)) >> 16;
}
__device__ __forceinline__ float bf_bits2f(unsigned b) {
    return __uint_as_float(b << 16);
}

// ---------------- K1: prep --------------------------------------------------
// W[r][K=64][kk=32], K slots [A(x2h) A(x2l) B(xh) B(xl)], written in MFMA
// B-fragment order: wfrag[(((r*2+ks)*2+nt)*64 + lane)*8 + j]
__global__ __launch_bounds__(256) void prep_kernel(
    const float* __restrict__ means, const float* __restrict__ scales,
    unsigned short* __restrict__ wfrag, float* __restrict__ cv)
{
    int p = blockIdx.x * 256 + threadIdx.x;   // p = r*32 + kk
    if (p >= NR * NK) return;
    int n  = p & 15;
    int nt = (p >> 4) & 1;
    int r  = p >> 5;

    const float* m = means  + (size_t)p * ND;
    const float* s = scales + (size_t)p * ND;
    float Av[ND], Bv[ND];
    float csum = 0.f;
#pragma unroll
    for (int d = 0; d < ND; ++d) {
        float sd = s[d], md = m[d];
        float a  = 1.0f / sd;
        float a2 = a * a;
        Av[d] = -0.5f * a2;
        Bv[d] = md * a2;
        float c = md * a;
        csum += -0.5f * c * c - logf(sd);
    }
    cv[p] = csum - HALF_D_LOG2PI;

#pragma unroll
    for (int slot = 0; slot < 4; ++slot) {
        int ks = slot >> 1;
#pragma unroll
        for (int d = 0; d < ND; ++d) {
            int Kin  = (slot & 1) * 16 + d;
            int quad = Kin >> 3;
            int j    = Kin & 7;
            int lane = quad * 16 + n;
            size_t idx = ((((size_t)r * 2 + ks) * 2 + nt) * 64 + lane) * 8 + j;
            float v = (slot < 2) ? Av[d] : Bv[d];
            wfrag[idx] = (unsigned short)f2bf_bits(v);
        }
    }
}

// ---------------- K2: fused gather + transform + MFMA -----------------------
// Block: 16 b-rows x 32 r's. LDS phase 1: xs[16][1028] + ridx[32][17].
// Phase 2: gather to 64 held VGPRs/thread. Phase 3 (aliased LDS): per 16-r
// chunk, write A-frag rows (stride 72 shorts = 144B, 16B-aligned), MFMA, store.
__global__ __launch_bounds__(256, 2) void fused_kernel(
    const float* __restrict__ x, const int* __restrict__ regions,
    const unsigned short* __restrict__ wfrag, const float* __restrict__ cv,
    float* __restrict__ out)
{
    __shared__ __align__(16) char lds[16 * 1028 * 4 + 32 * 17 * 4];  // 67968 B
    float* xs = (float*)lds;                         // [16][1028]
    int*   ridx = (int*)(lds + 16 * 1028 * 4);       // [32][17]
    unsigned short* xg = (unsigned short*)lds;       // [256][72] (aliased)

    const int t  = threadIdx.x;
    const int bt = blockIdx.x;          // b-tile: b0 = bt*16
    const int r0 = blockIdx.y * 32;     // r-half
    const int b0 = bt * 16;

    // ---- phase 1: stage indices + x rows ----
    for (int j = t; j < 32 * ND; j += 256) {
        int rl = j >> 4, d = j & 15;
        ridx[rl * 17 + d] = regions[(r0 + rl) * ND + d];
    }
    {
        const float4* src = (const float4*)(x + (size_t)b0 * NF);
#pragma unroll
        for (int i = 0; i < 16; ++i)
            *(float4*)(xs + i * 1028 + t * 4) = src[i * 256 + t];
    }
    __syncthreads();

    // ---- phase 2: gather + square + bf16 hi/lo split to registers ----
    const int rl = t & 31;              // r within half
    const int bA = t >> 5;              // 0..7 (pair 2 adds 8)
    int idxv[ND];
#pragma unroll
    for (int d = 0; d < ND; ++d) idxv[d] = ridx[rl * 17 + d];

    unsigned pk[2][32];
#pragma unroll
    for (int pp = 0; pp < 2; ++pp) {
        const int b = bA + pp * 8;
#pragma unroll
        for (int d = 0; d < ND; d += 2) {
            float x0 = xs[b * 1028 + idxv[d]];
            float x1 = xs[b * 1028 + idxv[d + 1]];
            float q0 = x0 * x0, q1 = x1 * x1;
            unsigned h20 = f2bf_bits(q0), h21 = f2bf_bits(q1);
            unsigned l20 = f2bf_bits(q0 - bf_bits2f(h20));
            unsigned l21 = f2bf_bits(q1 - bf_bits2f(h21));
            unsigned h0  = f2bf_bits(x0), h1 = f2bf_bits(x1);
            unsigned l0  = f2bf_bits(x0 - bf_bits2f(h0));
            unsigned l1  = f2bf_bits(x1 - bf_bits2f(h1));
            int di = d >> 1;
            pk[pp][di]      = h20 | (h21 << 16);
            pk[pp][8 + di]  = l20 | (l21 << 16);
            pk[pp][16 + di] = h0  | (h1 << 16);
            pk[pp][24 + di] = l0  | (l1 << 16);
        }
    }
    __syncthreads();    // xs/ridx dead; LDS now reused as xg

    // ---- phase 3: per 16-r chunk: write A-frags, MFMA, store ----
    const int wv   = t >> 6;
    const int L    = t & 63;
    const int m    = L & 15;
    const int quad = L >> 4;
    const short* wfs = (const short*)wfrag;

#pragma unroll
    for (int c = 0; c < 2; ++c) {
        if ((rl >> 4) == c) {
            int rr = rl & 15;
#pragma unroll
            for (int pp = 0; pp < 2; ++pp) {
                int b = bA + pp * 8;
                uint4* d4 = (uint4*)(xg + (rr * 16 + b) * 72);
#pragma unroll
                for (int q = 0; q < 8; ++q) d4[q] = ((uint4*)pk[pp])[q];
            }
        }
        __syncthreads();

#pragma unroll
        for (int i = 0; i < 4; ++i) {
            int rloc = wv * 4 + i;                 // r within chunk
            int r    = r0 + c * 16 + rloc;
            const unsigned short* arow = xg + (rloc * 16 + m) * 72;
            short8 a0 = *(const short8*)(arow + quad * 8);
            short8 a1 = *(const short8*)(arow + 32 + quad * 8);

            size_t wb = ((size_t)r * 4) * 512 + (size_t)L * 8;
            short8 w00 = *(const short8*)(wfs + wb);
            short8 w01 = *(const short8*)(wfs + wb + 512);
            short8 w10 = *(const short8*)(wfs + wb + 1024);
            short8 w11 = *(const short8*)(wfs + wb + 1536);

            floatx4 acc0 = {0.f, 0.f, 0.f, 0.f};
            floatx4 acc1 = {0.f, 0.f, 0.f, 0.f};
            acc0 = __builtin_amdgcn_mfma_f32_16x16x32_bf16(a0, w00, acc0, 0, 0, 0);
            acc0 = __builtin_amdgcn_mfma_f32_16x16x32_bf16(a1, w10, acc0, 0, 0, 0);
            acc1 = __builtin_amdgcn_mfma_f32_16x16x32_bf16(a0, w01, acc1, 0, 0, 0);
            acc1 = __builtin_amdgcn_mfma_f32_16x16x32_bf16(a1, w11, acc1, 0, 0, 0);

            float c0 = cv[r * NK + m];
            float c1 = cv[r * NK + 16 + m];
            int brow = bt * 16 + quad * 4;
#pragma unroll
            for (int g = 0; g < 4; ++g) {
                size_t ob = (size_t)(brow + g) * (NR * NK) + (size_t)r * NK;
                out[ob + m]      = acc0[g] + c0;
                out[ob + 16 + m] = acc1[g] + c1;
            }
        }
        __syncthreads();
    }
}

extern "C" void kernel_launch(void* const* d_in, const int* in_sizes, int n_in,
                              void* d_out, int out_size, void* d_ws, size_t ws_size,
                              hipStream_t stream) {
    const float* x       = (const float*)d_in[0];
    const int*   regions = (const int*)d_in[1];
    const float* means   = (const float*)d_in[2];
    const float* scales  = (const float*)d_in[3];
    float* out = (float*)d_out;

    char* ws = (char*)d_ws;
    unsigned short* wfrag = (unsigned short*)ws;       // 256 KB
    float*          cvp   = (float*)(ws + 262144);     // 8 KB

    prep_kernel<<<dim3((NR * NK + 255) / 256), 256, 0, stream>>>(means, scales, wfrag, cvp);
    fused_kernel<<<dim3(NB / 16, 2), 256, 0, stream>>>(x, regions, wfrag, cvp, out);
}

// Round 5
// 85.560 us; speedup vs baseline: 1.2571x; 1.0519x over previous
//
#include <hip/hip_runtime.h>

typedef __attribute__((ext_vector_type(8))) short short8;
typedef __attribute__((ext_vector_type(4))) float floatx4;

#define NB 4096
#define NF 1024
#define NR 64
#define NK 32
#define ND 16
#define HALF_D_LOG2PI 14.702988531274762f

// bf16 helpers (finite values only; round-to-nearest-even)
__device__ __forceinline__ unsigned f2bf_bits(float f) {
    unsigned u = __float_as_uint(f);
    return (u + 0x7fffu + ((u >> 16) & 1u)) >> 16;
}
__device__ __forceinline__ float bf_bits2f(unsigned b) {
    return __uint_as_float(b << 16);
}

// ---------------- K1: prep (one block per r, coalesced uint4 writes) --------
// wfrag[(((r*2+ks)*2+nt)*64 + lane)*8 + j] holds bf16 of
//   (ks==0 ? A : B)[r][nt*16 + (lane&15)][((lane>>4)*8 + j) & 15]
// A = -0.5/s^2 (multiplies x2h and x2l slots), B = m/s^2 (xh, xl slots).
__global__ __launch_bounds__(256) void prep_kernel(
    const float* __restrict__ means, const float* __restrict__ scales,
    unsigned short* __restrict__ wfrag, float* __restrict__ cv)
{
    __shared__ float Asm[NK][ND];
    __shared__ float Bsm[NK][ND];
    __shared__ float csum[NK][8];
    const int r = blockIdx.x;
    const int t = threadIdx.x;

    {   // compute A,B and log-det partials: 2 (k,d) elems per thread
        int k  = t >> 3;
        int d0 = (t & 7) * 2;
        const float* m = means  + ((size_t)r * NK + k) * ND + d0;
        const float* s = scales + ((size_t)r * NK + k) * ND + d0;
        float partial = 0.f;
#pragma unroll
        for (int q = 0; q < 2; ++q) {
            float sd = s[q], md = m[q];
            float a  = 1.f / sd;
            float a2 = a * a;
            Asm[k][d0 + q] = -0.5f * a2;
            Bsm[k][d0 + q] = md * a2;
            float c = md * a;
            partial += -0.5f * c * c - logf(sd);
        }
        csum[k][t & 7] = partial;
    }
    __syncthreads();
    if (t < NK) {
        float acc = 0.f;
#pragma unroll
        for (int q = 0; q < 8; ++q) acc += csum[t][q];
        cv[r * NK + t] = acc - HALF_D_LOG2PI;
    }

    // emit this r's 4 KB of fragments: one uint4 per thread, coalesced
    const int ks   = t >> 7;
    const int nt   = (t >> 6) & 1;
    const int lane = t & 63;
    const int n    = lane & 15;
    const int qd   = lane >> 4;
    const int kk   = nt * 16 + n;
    unsigned px[4];
#pragma unroll
    for (int j2 = 0; j2 < 4; ++j2) {
        int j  = j2 * 2;
        int d0 = (qd * 8 + j) & 15;
        int d1 = (qd * 8 + j + 1) & 15;
        float v0 = ks ? Bsm[kk][d0] : Asm[kk][d0];
        float v1 = ks ? Bsm[kk][d1] : Asm[kk][d1];
        px[j2] = f2bf_bits(v0) | (f2bf_bits(v1) << 16);
    }
    *(uint4*)(wfrag + ((((size_t)r * 2 + ks) * 2 + nt) * 64 + lane) * 8) = *(uint4*)px;
}

// ---------------- K2: fused gather + transform + MFMA -----------------------
// Block: 16 b-rows x 32 r's. Phase 1: xs[16][1028] + ridx[32][17] in LDS.
// Phase 2: gather+square+bf16 hi/lo split to 64 VGPRs/thread.
// Phase 3 (LDS aliased): 512 A-frag rows, stride 72 shorts; the eight 16B
// chunks of each row are XOR-permuted by s=(row>>4)&7 (stays IN the row:
// this is the R4 bug fix). One barrier, then MFMA + store.
__global__ __launch_bounds__(256, 2) void fused_kernel(
    const float* __restrict__ x, const int* __restrict__ regions,
    const unsigned short* __restrict__ wfrag, const float* __restrict__ cv,
    float* __restrict__ out)
{
    __shared__ __align__(16) char lds[73728];        // max(67968, 512*72*2)
    float* xs   = (float*)lds;                       // [16][1028]
    int*   ridx = (int*)(lds + 16 * 1028 * 4);       // [32][17]
    unsigned short* xg = (unsigned short*)lds;       // [512 rows][72] xor-swz

    const int t  = threadIdx.x;
    const int bt = blockIdx.x;
    const int r0 = blockIdx.y * 32;
    const int b0 = bt * 16;

    // ---- phase 1: stage indices + x rows ----
    for (int j = t; j < 32 * ND; j += 256) {
        int rr = j >> 4, d = j & 15;
        ridx[rr * 17 + d] = regions[(r0 + rr) * ND + d];
    }
    {
        const float4* src = (const float4*)(x + (size_t)b0 * NF);
#pragma unroll
        for (int i = 0; i < 16; ++i)
            *(float4*)(xs + i * 1028 + t * 4) = src[i * 256 + t];
    }
    __syncthreads();

    // ---- phase 2: gather + square + bf16 hi/lo split into registers ----
    const int rl = t & 31;
    const int bA = t >> 5;
    int idxv[ND];
#pragma unroll
    for (int d = 0; d < ND; ++d) idxv[d] = ridx[rl * 17 + d];

    unsigned pk[2][32];
#pragma unroll
    for (int pp = 0; pp < 2; ++pp) {
        const int b = bA + pp * 8;
#pragma unroll
        for (int d = 0; d < ND; d += 2) {
            float x0 = xs[b * 1028 + idxv[d]];
            float x1 = xs[b * 1028 + idxv[d + 1]];
            float q0 = x0 * x0, q1 = x1 * x1;
            unsigned h20 = f2bf_bits(q0), h21 = f2bf_bits(q1);
            unsigned l20 = f2bf_bits(q0 - bf_bits2f(h20));
            unsigned l21 = f2bf_bits(q1 - bf_bits2f(h21));
            unsigned h0  = f2bf_bits(x0), h1 = f2bf_bits(x1);
            unsigned l0  = f2bf_bits(x0 - bf_bits2f(h0));
            unsigned l1  = f2bf_bits(x1 - bf_bits2f(h1));
            int di = d >> 1;
            pk[pp][di]      = h20 | (h21 << 16);
            pk[pp][8 + di]  = l20 | (l21 << 16);
            pk[pp][16 + di] = h0  | (h1 << 16);
            pk[pp][24 + di] = l0  | (l1 << 16);
        }
    }
    __syncthreads();    // xs/ridx dead; LDS becomes xg

    // ---- phase 3: write all A-frags once (XOR chunk swizzle, in-row) ----
    {
        const int s = rl & 7;            // = (row>>4)&7 for both pp rows
#pragma unroll
        for (int pp = 0; pp < 2; ++pp) {
            int row = rl * 16 + bA + pp * 8;
            uint4* base = (uint4*)(xg + row * 72);
#pragma unroll
            for (int q = 0; q < 8; ++q) base[q ^ s] = ((uint4*)pk[pp])[q];
        }
    }
    __syncthreads();

    const int wv   = t >> 6;
    const int L    = t & 63;
    const int col  = L & 15;
    const int quad = L >> 4;
    const short* wfs = (const short*)wfrag;

#pragma unroll 2
    for (int i = 0; i < 8; ++i) {
        int rloc = wv * 8 + i;
        int r    = r0 + rloc;
        int row  = rloc * 16 + col;      // A-row b-local = col
        int s    = rloc & 7;             // = (row>>4)&7, wave-uniform
        const uint4* base = (const uint4*)(xg + row * 72);
        uint4 ca0 = base[quad ^ s];          // logical chunk quad   (K 0..31)
        uint4 ca1 = base[(4 + quad) ^ s];    // logical chunk 4+quad (K 32..63)
        short8 a0 = *(short8*)&ca0;
        short8 a1 = *(short8*)&ca1;

        size_t wb = ((size_t)r * 4) * 512 + (size_t)L * 8;
        short8 w00 = *(const short8*)(wfs + wb);
        short8 w01 = *(const short8*)(wfs + wb + 512);
        short8 w10 = *(const short8*)(wfs + wb + 1024);
        short8 w11 = *(const short8*)(wfs + wb + 1536);

        floatx4 acc0 = {0.f, 0.f, 0.f, 0.f};
        floatx4 acc1 = {0.f, 0.f, 0.f, 0.f};
        acc0 = __builtin_amdgcn_mfma_f32_16x16x32_bf16(a0, w00, acc0, 0, 0, 0);
        acc0 = __builtin_amdgcn_mfma_f32_16x16x32_bf16(a1, w10, acc0, 0, 0, 0);
        acc1 = __builtin_amdgcn_mfma_f32_16x16x32_bf16(a0, w01, acc1, 0, 0, 0);
        acc1 = __builtin_amdgcn_mfma_f32_16x16x32_bf16(a1, w11, acc1, 0, 0, 0);

        float c0 = cv[r * NK + col];
        float c1 = cv[r * NK + 16 + col];
        int brow = bt * 16 + quad * 4;
#pragma unroll
        for (int g = 0; g < 4; ++g) {
            size_t ob = (size_t)(brow + g) * (NR * NK) + (size_t)r * NK;
            out[ob + col]      = acc0[g] + c0;
            out[ob + 16 + col] = acc1[g] + c1;
        }
    }
}

extern "C" void kernel_launch(void* const* d_in, const int* in_sizes, int n_in,
                              void* d_out, int out_size, void* d_ws, size_t ws_size,
                              hipStream_t stream) {
    const float* x       = (const float*)d_in[0];
    const int*   regions = (const int*)d_in[1];
    const float* means   = (const float*)d_in[2];
    const float* scales  = (const float*)d_in[3];
    float* out = (float*)d_out;

    char* ws = (char*)d_ws;
    unsigned short* wfrag = (unsigned short*)ws;       // 256 KB
    float*          cvp   = (float*)(ws + 262144);     // 8 KB

    prep_kernel<<<dim3(NR), 256, 0, stream>>>(means, scales, wfrag, cvp);
    fused_kernel<<<dim3(NB / 16, 2), 256, 0, stream>>>(x, regions, wfrag, cvp, out);
}

// Round 7
// 83.495 us; speedup vs baseline: 1.2882x; 1.0247x over previous
//
#include <hip/hip_runtime.h>

typedef __attribute__((ext_vector_type(8))) short short8;
typedef __attribute__((ext_vector_type(4))) float floatx4;

#define NB 4096
#define NF 1024
#define NR 64
#define NK 32
#define ND 16
#define HALF_D_LOG2PI 14.702988531274762f

// bf16 helpers (finite values only; round-to-nearest-even)
__device__ __forceinline__ unsigned f2bf_bits(float f) {
    unsigned u = __float_as_uint(f);
    return (u + 0x7fffu + ((u >> 16) & 1u)) >> 16;
}

// ---------------- K1: prep (one block per r) --------------------------------
// K=32 layout. wfrag[(((r*2)+nt)*64 + lane)*8 + j] = bf16 of
//   W[r][kk=nt*16+(lane&15)][K=(lane>>4)*8+j],  K<16 -> A[d=K], K>=16 -> B[d=K-16]
// A = -0.5/s^2 (multiplies x2h), B = m/s^2 (multiplies xh).
__global__ __launch_bounds__(256) void prep_kernel(
    const float* __restrict__ means, const float* __restrict__ scales,
    unsigned short* __restrict__ wfrag, float* __restrict__ cv)
{
    __shared__ float Asm[NK][ND];
    __shared__ float Bsm[NK][ND];
    __shared__ float csum[NK][8];
    const int r = blockIdx.x;
    const int t = threadIdx.x;

    {   // A,B and log-det partials: 2 (k,d) elems per thread
        int k  = t >> 3;
        int d0 = (t & 7) * 2;
        const float* m = means  + ((size_t)r * NK + k) * ND + d0;
        const float* s = scales + ((size_t)r * NK + k) * ND + d0;
        float partial = 0.f;
#pragma unroll
        for (int q = 0; q < 2; ++q) {
            float sd = s[q], md = m[q];
            float a  = 1.f / sd;
            float a2 = a * a;
            Asm[k][d0 + q] = -0.5f * a2;
            Bsm[k][d0 + q] = md * a2;
            float c = md * a;
            partial += -0.5f * c * c - logf(sd);
        }
        csum[k][t & 7] = partial;
    }
    __syncthreads();
    if (t < NK) {
        float acc = 0.f;
#pragma unroll
        for (int q = 0; q < 8; ++q) acc += csum[t][q];
        cv[r * NK + t] = acc - HALF_D_LOG2PI;
    }

    if (t < 128) {   // emit this r's 2 KB of B-fragments, coalesced uint4
        const int nt   = t >> 6;
        const int lane = t & 63;
        const int n    = lane & 15;
        const int qd   = lane >> 4;
        const int kk   = nt * 16 + n;
        unsigned px[4];
#pragma unroll
        for (int j2 = 0; j2 < 4; ++j2) {
            int K0 = qd * 8 + j2 * 2;
            int K1 = K0 + 1;
            float v0 = (K0 < 16) ? Asm[kk][K0] : Bsm[kk][K0 - 16];
            float v1 = (K1 < 16) ? Asm[kk][K1] : Bsm[kk][K1 - 16];
            px[j2] = f2bf_bits(v0) | (f2bf_bits(v1) << 16);
        }
        *(uint4*)(wfrag + (((size_t)r * 2 + nt) * 64 + lane) * 8) = *(uint4*)px;
    }
}

// ---------------- K2: fused gather + transform + MFMA (K=32) ----------------
// Block: 16 b x 32 r, 512 threads (8 waves) -> 2 blocks/CU = 16 waves/CU.
// Phase 1: xs[16][1028] + ridx[32][17]. Phase 2: 1 (b,r) pair/thread ->
// pk[16] dwords = [x2h(8) | xh(8)]. Phase 3 (aliased LDS): xg rows of 16
// dwords, stride 20; the four 16B chunks of each row are XOR-permuted by
// s = (row>>4)&3 — permutation stays IN the row (R4/R6 overflow-bug class
// eliminated by construction). One barrier, 2 MFMAs + stores per r.
__global__ __launch_bounds__(512, 4) void fused_kernel(
    const float* __restrict__ x, const int* __restrict__ regions,
    const unsigned short* __restrict__ wfrag, const float* __restrict__ cv,
    float* __restrict__ out)
{
    __shared__ __align__(16) char lds[67968];    // xs+ridx; xg (40KB) aliases
    float*    xs   = (float*)lds;                // [16][1028]
    int*      ridx = (int*)(lds + 16 * 1028 * 4);// [32][17]
    unsigned* xgd  = (unsigned*)lds;             // dword-indexed frag store

    const int t  = threadIdx.x;                  // 0..511
    const int bt = blockIdx.x;
    const int r0 = blockIdx.y * 32;
    const int b0 = bt * 16;

    // ---- phase 1: stage indices + x rows ----
    {
        int rr = t >> 4, d = t & 15;             // exactly 512 entries
        ridx[rr * 17 + d] = regions[(r0 + rr) * ND + d];
    }
    {
        const float4* src = (const float4*)(x + (size_t)b0 * NF);
#pragma unroll
        for (int i = 0; i < 8; ++i) {
            int j = t + i * 512;
            int row = j >> 8, c4 = j & 255;
            *(float4*)(xs + row * 1028 + c4 * 4) = src[row * 256 + c4];
        }
    }
    __syncthreads();

    // ---- phase 2: gather + square + bf16 pack (1 pair/thread) ----
    const int rl = t & 31;
    const int bb = t >> 5;
    int idxv[ND];
#pragma unroll
    for (int d = 0; d < ND; ++d) idxv[d] = ridx[rl * 17 + d];

    unsigned pk[16];
#pragma unroll
    for (int d = 0; d < ND; d += 2) {
        float x0 = xs[bb * 1028 + idxv[d]];
        float x1 = xs[bb * 1028 + idxv[d + 1]];
        pk[d >> 1]       = f2bf_bits(x0 * x0) | (f2bf_bits(x1 * x1) << 16);
        pk[8 + (d >> 1)] = f2bf_bits(x0)      | (f2bf_bits(x1)      << 16);
    }
    __syncthreads();    // xs/ridx dead; LDS becomes xg

    // ---- phase 3: write frag rows (XOR chunk swizzle, in-row) ----
    {
        int row = rl * 16 + bb;                  // row>>4 == rl
        int s   = rl & 3;
        unsigned* wp = xgd + row * 20;
#pragma unroll
        for (int c = 0; c < 4; ++c)
            *(uint4*)(wp + ((c ^ s) << 2)) = ((uint4*)pk)[c];
    }
    __syncthreads();

    const int wv   = t >> 6;
    const int L    = t & 63;
    const int col  = L & 15;
    const int quad = L >> 4;
    const short* wfs = (const short*)wfrag;

#pragma unroll
    for (int i = 0; i < 4; ++i) {
        int rloc = wv * 4 + i;
        int r    = r0 + rloc;
        int row  = rloc * 16 + col;              // row>>4 == rloc
        int s    = rloc & 3;                     // wave-uniform
        const unsigned* rp = xgd + row * 20;
        uint4 ca = *(const uint4*)(rp + ((quad ^ s) << 2));
        short8 a = *(short8*)&ca;

        size_t wb = (size_t)r * 2 * 512 + (size_t)L * 8;
        short8 w0 = *(const short8*)(wfs + wb);          // kk 0..15
        short8 w1 = *(const short8*)(wfs + wb + 512);    // kk 16..31

        floatx4 z = {0.f, 0.f, 0.f, 0.f};
        floatx4 acc0 = __builtin_amdgcn_mfma_f32_16x16x32_bf16(a, w0, z, 0, 0, 0);
        floatx4 acc1 = __builtin_amdgcn_mfma_f32_16x16x32_bf16(a, w1, z, 0, 0, 0);

        float c0 = cv[r * NK + col];
        float c1 = cv[r * NK + 16 + col];
        int brow = bt * 16 + quad * 4;
#pragma unroll
        for (int g = 0; g < 4; ++g) {
            size_t ob = (size_t)(brow + g) * (NR * NK) + (size_t)r * NK;
            out[ob + col]      = acc0[g] + c0;
            out[ob + 16 + col] = acc1[g] + c1;
        }
    }
}

extern "C" void kernel_launch(void* const* d_in, const int* in_sizes, int n_in,
                              void* d_out, int out_size, void* d_ws, size_t ws_size,
                              hipStream_t stream) {
    const float* x       = (const float*)d_in[0];
    const int*   regions = (const int*)d_in[1];
    const float* means   = (const float*)d_in[2];
    const float* scales  = (const float*)d_in[3];
    float* out = (float*)d_out;

    char* ws = (char*)d_ws;
    unsigned short* wfrag = (unsigned short*)ws;       // 128 KB
    float*          cvp   = (float*)(ws + 131072);     // 8 KB

    prep_kernel<<<dim3(NR), 256, 0, stream>>>(means, scales, wfrag, cvp);
    fused_kernel<<<dim3(NB / 16, 2), 512, 0, stream>>>(x, regions, wfrag, cvp, out);
}

// Round 8
// 83.078 us; speedup vs baseline: 1.2947x; 1.0050x over previous
//
#include <hip/hip_runtime.h>

typedef __attribute__((ext_vector_type(8))) short short8;
typedef __attribute__((ext_vector_type(4))) float floatx4;

#define NB 4096
#define NF 1024
#define NR 64
#define NK 32
#define ND 16
#define HALF_D_LOG2PI 14.702988531274762f

// bf16 helpers (finite values only; round-to-nearest-even)
__device__ __forceinline__ unsigned f2bf_bits(float f) {
    unsigned u = __float_as_uint(f);
    return (u + 0x7fffu + ((u >> 16) & 1u)) >> 16;
}

// ---------------- K1: prep (one block per r) --------------------------------
// K=32 layout. wfrag[(((r*2)+nt)*64 + lane)*8 + j] = bf16 of
//   W[r][kk=nt*16+(lane&15)][K=(lane>>4)*8+j],  K<16 -> A[d=K], K>=16 -> B[d=K-16]
// A = -0.5/s^2 (multiplies x2h), B = m/s^2 (multiplies xh).
__global__ __launch_bounds__(256) void prep_kernel(
    const float* __restrict__ means, const float* __restrict__ scales,
    unsigned short* __restrict__ wfrag, float* __restrict__ cv)
{
    __shared__ float Asm[NK][ND];
    __shared__ float Bsm[NK][ND];
    __shared__ float csum[NK][8];
    const int r = blockIdx.x;
    const int t = threadIdx.x;

    {   // A,B and log-det partials: 2 (k,d) elems per thread
        int k  = t >> 3;
        int d0 = (t & 7) * 2;
        const float* m = means  + ((size_t)r * NK + k) * ND + d0;
        const float* s = scales + ((size_t)r * NK + k) * ND + d0;
        float partial = 0.f;
#pragma unroll
        for (int q = 0; q < 2; ++q) {
            float sd = s[q], md = m[q];
            float a  = 1.f / sd;
            float a2 = a * a;
            Asm[k][d0 + q] = -0.5f * a2;
            Bsm[k][d0 + q] = md * a2;
            float c = md * a;
            partial += -0.5f * c * c - logf(sd);
        }
        csum[k][t & 7] = partial;
    }
    __syncthreads();
    if (t < NK) {
        float acc = 0.f;
#pragma unroll
        for (int q = 0; q < 8; ++q) acc += csum[t][q];
        cv[r * NK + t] = acc - HALF_D_LOG2PI;
    }

    if (t < 128) {   // emit this r's 2 KB of B-fragments, coalesced uint4
        const int nt   = t >> 6;
        const int lane = t & 63;
        const int n    = lane & 15;
        const int qd   = lane >> 4;
        const int kk   = nt * 16 + n;
        unsigned px[4];
#pragma unroll
        for (int j2 = 0; j2 < 4; ++j2) {
            int K0 = qd * 8 + j2 * 2;
            int K1 = K0 + 1;
            float v0 = (K0 < 16) ? Asm[kk][K0] : Bsm[kk][K0 - 16];
            float v1 = (K1 < 16) ? Asm[kk][K1] : Bsm[kk][K1 - 16];
            px[j2] = f2bf_bits(v0) | (f2bf_bits(v1) << 16);
        }
        *(uint4*)(wfrag + (((size_t)r * 2 + nt) * 64 + lane) * 8) = *(uint4*)px;
    }
}

// ---------------- K2: fused gather + transform + MFMA (K=32, full-r) --------
// Grid 256 blocks; block = 16 b x ALL 64 r, 512 threads (8 waves).
// x is read from HBM exactly once. Phase 1: xs[16][1028] + ridx[64][17]
// (70.1 KB). Phase 2: 2 (b,r) pairs/thread. Phase 3 (aliased LDS): xg = 1024
// rows x 20 dwords (80 KB cap -> 2 blocks/CU, 16 waves/CU); four 16B chunks
// of each row XOR-permuted by s=(row>>4)&3 (in-row by construction). One
// barrier, then 8 r-iters/wave: 2 MFMAs + stores each.
__global__ __launch_bounds__(512, 4) void fused_kernel(
    const float* __restrict__ x, const int* __restrict__ regions,
    const unsigned short* __restrict__ wfrag, const float* __restrict__ cv,
    float* __restrict__ out)
{
    __shared__ __align__(16) char lds[81920];     // max(70144, 1024*20*4)
    float*    xs   = (float*)lds;                 // [16][1028]
    int*      ridx = (int*)(lds + 16 * 1028 * 4); // [64][17]
    unsigned* xgd  = (unsigned*)lds;              // dword-indexed frag store

    const int t  = threadIdx.x;                   // 0..511
    const int bt = blockIdx.x;
    const int b0 = bt * 16;

    // ---- phase 1: stage indices + x rows ----
#pragma unroll
    for (int j = t; j < NR * ND; j += 512) {      // 1024 entries, 2/thread
        int rr = j >> 4, d = j & 15;
        ridx[rr * 17 + d] = regions[j];
    }
    {
        const float4* src = (const float4*)(x + (size_t)b0 * NF);
#pragma unroll
        for (int i = 0; i < 8; ++i) {
            int j = t + i * 512;
            int row = j >> 8, c4 = j & 255;
            *(float4*)(xs + row * 1028 + c4 * 4) = src[row * 256 + c4];
        }
    }
    __syncthreads();

    // ---- phase 2: gather + square + bf16 pack (2 pairs/thread) ----
    const int rl = t >> 3;                        // 0..63
    const int bb = t & 7;                         // pairs: bb and bb+8
    int idxv[ND];
#pragma unroll
    for (int d = 0; d < ND; ++d) idxv[d] = ridx[rl * 17 + d];

    unsigned pk[2][16];
#pragma unroll
    for (int pp = 0; pp < 2; ++pp) {
        const int b = bb + pp * 8;
#pragma unroll
        for (int d = 0; d < ND; d += 2) {
            float x0 = xs[b * 1028 + idxv[d]];
            float x1 = xs[b * 1028 + idxv[d + 1]];
            pk[pp][d >> 1]       = f2bf_bits(x0 * x0) | (f2bf_bits(x1 * x1) << 16);
            pk[pp][8 + (d >> 1)] = f2bf_bits(x0)      | (f2bf_bits(x1)      << 16);
        }
    }
    __syncthreads();    // xs/ridx dead; LDS becomes xg

    // ---- phase 3: write frag rows (XOR chunk swizzle, in-row) ----
    {
        const int s = rl & 3;                     // = (row>>4)&3 for both rows
#pragma unroll
        for (int pp = 0; pp < 2; ++pp) {
            int row = rl * 16 + bb + pp * 8;
            unsigned* wp = xgd + row * 20;
#pragma unroll
            for (int c = 0; c < 4; ++c)
                *(uint4*)(wp + ((c ^ s) << 2)) = ((uint4*)pk[pp])[c];
        }
    }
    __syncthreads();

    const int wv   = t >> 6;
    const int L    = t & 63;
    const int col  = L & 15;
    const int quad = L >> 4;
    const short* wfs = (const short*)wfrag;

#pragma unroll 2
    for (int i = 0; i < 8; ++i) {
        int r   = wv * 8 + i;                     // 0..63
        int row = r * 16 + col;                   // row>>4 == r
        int s   = r & 3;                          // wave-uniform
        const unsigned* rp = xgd + row * 20;
        uint4 ca = *(const uint4*)(rp + ((quad ^ s) << 2));
        short8 a = *(short8*)&ca;

        size_t wb = (size_t)r * 2 * 512 + (size_t)L * 8;
        short8 w0 = *(const short8*)(wfs + wb);          // kk 0..15
        short8 w1 = *(const short8*)(wfs + wb + 512);    // kk 16..31

        floatx4 z = {0.f, 0.f, 0.f, 0.f};
        floatx4 acc0 = __builtin_amdgcn_mfma_f32_16x16x32_bf16(a, w0, z, 0, 0, 0);
        floatx4 acc1 = __builtin_amdgcn_mfma_f32_16x16x32_bf16(a, w1, z, 0, 0, 0);

        float c0 = cv[r * NK + col];
        float c1 = cv[r * NK + 16 + col];
        int brow = bt * 16 + quad * 4;
#pragma unroll
        for (int g = 0; g < 4; ++g) {
            size_t ob = (size_t)(brow + g) * (NR * NK) + (size_t)r * NK;
            out[ob + col]      = acc0[g] + c0;
            out[ob + 16 + col] = acc1[g] + c1;
        }
    }
}

extern "C" void kernel_launch(void* const* d_in, const int* in_sizes, int n_in,
                              void* d_out, int out_size, void* d_ws, size_t ws_size,
                              hipStream_t stream) {
    const float* x       = (const float*)d_in[0];
    const int*   regions = (const int*)d_in[1];
    const float* means   = (const float*)d_in[2];
    const float* scales  = (const float*)d_in[3];
    float* out = (float*)d_out;

    char* ws = (char*)d_ws;
    unsigned short* wfrag = (unsigned short*)ws;       // 128 KB
    float*          cvp   = (float*)(ws + 131072);     // 8 KB

    prep_kernel<<<dim3(NR), 256, 0, stream>>>(means, scales, wfrag, cvp);
    fused_kernel<<<dim3(NB / 16), 512, 0, stream>>>(x, regions, wfrag, cvp, out);
}